// Round 6
// baseline (5063.487 us; speedup 1.0000x reference)
//
#include <hip/hip_runtime.h>
#include <hip/hip_bf16.h>
#include <cstddef>

#define CC 1024   // states
#define HH 256    // hidden
#define VV 10000  // vocab
#define NN 16     // batch
#define TT 256    // time
#define NB 16     // blocks in k_fwd
#define SENT64 0xFFFFFFFFFFFFFFFFull

typedef __attribute__((ext_vector_type(8))) short s8b;
typedef __attribute__((ext_vector_type(4))) float f32x4;

__device__ __forceinline__ unsigned short f2bf(float f) {
    unsigned int b = __builtin_bit_cast(unsigned int, f);
    b += 0x7FFFu + ((b >> 16) & 1u);
    return (unsigned short)(b >> 16);
}
__device__ __forceinline__ float bf2f(unsigned short u) {
    return __builtin_bit_cast(float, ((unsigned int)u) << 16);
}

// ---------------- residual MLP: out = relu(relu(x@w1+b1)@w2+b2) + x ----------------
struct ResArgs { const float *x, *w1, *b1, *w2, *b2; float* o; };
struct ResArgs3 { ResArgs a[3]; };

__global__ __launch_bounds__(256) void k_res(ResArgs3 A)
{
    ResArgs R = A.a[blockIdx.y];
    const int r0 = blockIdx.x * 16;
    const int th = threadIdx.x;
    __shared__ float xs[256][24];
    __shared__ float hs[256][24];
    #pragma unroll
    for (int k = 0; k < 16; k++) xs[th][k] = R.x[(size_t)(r0 + k) * HH + th];
    __syncthreads();
    float acc[16];
    float b1v = R.b1[th];
    #pragma unroll
    for (int r = 0; r < 16; r++) acc[r] = b1v;
    for (int h = 0; h < HH; h++) {
        float w = R.w1[(size_t)h * HH + th];
        #pragma unroll
        for (int r = 0; r < 16; r++) acc[r] = fmaf(xs[h][r], w, acc[r]);
    }
    #pragma unroll
    for (int r = 0; r < 16; r++) hs[th][r] = fmaxf(acc[r], 0.f);
    __syncthreads();
    float b2v = R.b2[th];
    #pragma unroll
    for (int r = 0; r < 16; r++) acc[r] = b2v;
    for (int h = 0; h < HH; h++) {
        float w = R.w2[(size_t)h * HH + th];
        #pragma unroll
        for (int r = 0; r < 16; r++) acc[r] = fmaf(hs[h][r], w, acc[r]);
    }
    #pragma unroll
    for (int r = 0; r < 16; r++) {
        size_t idx = (size_t)(r0 + r) * HH + th;
        R.o[idx] = fmaxf(acc[r], 0.f) + R.x[idx];
    }
}

// ---------------- start logits ----------------
__global__ __launch_bounds__(256) void k_slog(const float* __restrict__ res_s,
                                              const float* __restrict__ sw3,
                                              const float* __restrict__ sb3,
                                              float* __restrict__ slog)
{
    __shared__ float wv[256];
    const int th = threadIdx.x;
    const int c = blockIdx.x * 256 + th;
    wv[th] = sw3[th];
    __syncthreads();
    const float* row = res_s + (size_t)c * HH;
    float acc = 0.f;
    for (int h = 0; h < HH; h++) acc = fmaf(row[h], wv[h], acc);
    slog[c] = acc + sb3[0];
}

// ---------------- transition probs, transposed bf16: PB[j][i] = p(j | i) ----------------
__global__ __launch_bounds__(256) void k_pt(const float* __restrict__ res_t,
                                            const float* __restrict__ tw3,
                                            const float* __restrict__ tb3,
                                            unsigned short* __restrict__ PB)
{
    const int r0 = blockIdx.x * 4;
    const int th = threadIdx.x;
    __shared__ float rs[4][256];
    __shared__ float sred[256];
    for (int k = 0; k < 4; k++) rs[k][th] = res_t[(size_t)(r0 + k) * HH + th];
    __syncthreads();
    float acc[4][4];
    #pragma unroll
    for (int r = 0; r < 4; r++)
        #pragma unroll
        for (int q = 0; q < 4; q++) acc[r][q] = tb3[th + q * 256];
    for (int h = 0; h < HH; h++) {
        float w0 = tw3[(size_t)h * CC + th];
        float w1 = tw3[(size_t)h * CC + th + 256];
        float w2 = tw3[(size_t)h * CC + th + 512];
        float w3 = tw3[(size_t)h * CC + th + 768];
        #pragma unroll
        for (int r = 0; r < 4; r++) {
            float xv = rs[r][h];
            acc[r][0] = fmaf(xv, w0, acc[r][0]);
            acc[r][1] = fmaf(xv, w1, acc[r][1]);
            acc[r][2] = fmaf(xv, w2, acc[r][2]);
            acc[r][3] = fmaf(xv, w3, acc[r][3]);
        }
    }
    for (int r = 0; r < 4; r++) {
        float m = fmaxf(fmaxf(acc[r][0], acc[r][1]), fmaxf(acc[r][2], acc[r][3]));
        sred[th] = m; __syncthreads();
        for (int off = 128; off > 0; off >>= 1) { if (th < off) sred[th] = fmaxf(sred[th], sred[th + off]); __syncthreads(); }
        float rm = sred[0]; __syncthreads();
        float ssum = __expf(acc[r][0] - rm) + __expf(acc[r][1] - rm) + __expf(acc[r][2] - rm) + __expf(acc[r][3] - rm);
        sred[th] = ssum; __syncthreads();
        for (int off = 128; off > 0; off >>= 1) { if (th < off) sred[th] += sred[th + off]; __syncthreads(); }
        float inv = 1.0f / sred[0]; __syncthreads();
        #pragma unroll
        for (int q = 0; q < 4; q++) {
            float p = __expf(acc[r][q] - rm) * inv;
            PB[(size_t)(th + q * 256) * CC + (r0 + r)] = f2bf(p);   // [j][i]
        }
    }
}

// ---------------- emission logits bf16 + per-chunk LSE partials ----------------
__global__ __launch_bounds__(256) void k_emit(const float* __restrict__ res_e,
                                              const float* __restrict__ ew3,
                                              const float* __restrict__ eb3,
                                              unsigned short* __restrict__ emitT,
                                              float* __restrict__ epart)
{
    const int ct = blockIdx.x >> 2, jc = blockIdx.x & 3;
    const int c0 = ct * 16, j0 = jc * 2500;
    const int th = threadIdx.x;
    __shared__ float rs[256][24];
    __shared__ float sred[256];
    for (int k = 0; k < 16; k++) rs[th][k] = res_e[(size_t)(c0 + k) * HH + th];
    __syncthreads();
    float lm[16], ls[16];
    #pragma unroll
    for (int c = 0; c < 16; c++) { lm[c] = -1e30f; ls[c] = 0.f; }
    for (int it = 0; it < 10; it++) {
        int jo = it * 256 + th;
        if (jo < 2500) {
            int j = j0 + jo;
            float acc[16];
            float bb = eb3[j];
            #pragma unroll
            for (int c = 0; c < 16; c++) acc[c] = bb;
            for (int h = 0; h < HH; h++) {
                float wv = ew3[(size_t)h * VV + j];
                #pragma unroll
                for (int c = 0; c < 16; c++) acc[c] = fmaf(rs[h][c], wv, acc[c]);
            }
            #pragma unroll
            for (int c = 0; c < 16; c++) {
                emitT[(size_t)j * CC + c0 + c] = f2bf(acc[c]);
                float nm = fmaxf(lm[c], acc[c]);
                ls[c] = ls[c] * __expf(lm[c] - nm) + __expf(acc[c] - nm);
                lm[c] = nm;
            }
        }
    }
    for (int c = 0; c < 16; c++) {
        sred[th] = lm[c]; __syncthreads();
        for (int off = 128; off > 0; off >>= 1) { if (th < off) sred[th] = fmaxf(sred[th], sred[th + off]); __syncthreads(); }
        float gm = sred[0]; __syncthreads();
        sred[th] = (lm[c] > -1e29f) ? ls[c] * __expf(lm[c] - gm) : 0.f;
        __syncthreads();
        for (int off = 128; off > 0; off >>= 1) { if (th < off) sred[th] += sred[th + off]; __syncthreads(); }
        if (th == 0) {
            epart[((size_t)jc * CC + c0 + c) * 2]     = gm;
            epart[((size_t)jc * CC + c0 + c) * 2 + 1] = sred[0];
        }
        __syncthreads();
    }
}

// ---------------- combine epart -> lse[c] ----------------
__global__ __launch_bounds__(256) void k_lse(const float* __restrict__ epart,
                                             float* __restrict__ lse)
{
    int c = blockIdx.x * 256 + threadIdx.x;
    float M = -1e30f, S = 0.f;
    #pragma unroll
    for (int q = 0; q < 4; q++) {
        float m  = epart[((size_t)q * CC + c) * 2];
        float s2 = epart[((size_t)q * CC + c) * 2 + 1];
        float nm = fmaxf(M, m);
        S = S * __expf(M - nm) + s2 * __expf(m - nm);
        M = nm;
    }
    lse[c] = M + __logf(S);
}

// ---------------- in-place: emitT logits -> eprob = exp(logit - lse[c]) ----------------
__global__ __launch_bounds__(256) void k_eprob(unsigned short* __restrict__ emitT,
                                               const float* __restrict__ lse)
{
    __shared__ float ls[1024];
    const int th = threadIdx.x;
    for (int i = th; i < 1024; i += 256) ls[i] = lse[i];
    __syncthreads();
    size_t base = ((size_t)blockIdx.x * 256 + th) * 8;
    int c0 = (int)(base & 1023);
    s8b v = *(const s8b*)(emitT + base);
    unsigned short o[8];
    #pragma unroll
    for (int e = 0; e < 8; e++)
        o[e] = f2bf(__expf(bf2f((unsigned short)v[e]) - ls[c0 + e]));
    s8b ov;
    #pragma unroll
    for (int e = 0; e < 8; e++) ov[e] = (short)o[e];
    *(s8b*)(emitT + base) = ov;
}

// ---------------- forward scan: atomic sentinel exchange, time-indexed slots ----------------
// vbuf64 [TT][NN][CC/4] and parts64 [TT][128] are 0xFF-memset (sentinel = all-ones;
// impossible: every published value is >= 0 so sign bits are 0). All exchange ops are
// 8B agent-scope atomics: stores RELAXED (write-once slots, no WAR), first loads
// RELAXED, retry loads ACQUIRE (cache-invalidating -> guaranteed forward progress).
__global__ void __launch_bounds__(256, 1) k_fwd(
    const unsigned short* __restrict__ PB,    // [1024 j][1024 i] bf16
    const unsigned short* __restrict__ eprob, // [V][1024 c] bf16
    const float* __restrict__ slog,
    const int* __restrict__ text,
    unsigned long long* vbuf64,               // sentinel-armed
    unsigned long long* parts64,              // sentinel-armed
    float* __restrict__ outp)
{
    const int blk = blockIdx.x;
    const int th = threadIdx.x;
    const int w = th >> 6, l = th & 63;
    const int lhi = l >> 4, llo = l & 15;
    const int jglob = blk * 64 + w * 16 + llo;

    __shared__ int   toks[NN * TT];     // 16 KB
    __shared__ float ps_lds[256];
    __shared__ float sinv_lds[16];
    __shared__ float logacc[16];
    __shared__ float wpart[4][16];
    __shared__ __align__(16) unsigned short vtile[16][64];

    for (int i = th; i < NN * TT; i += 256) toks[i] = text[i];
    if (th < 16) logacc[th] = 0.f;

    // B fragments: wave's 16 columns, K=1024 -> 32 tiles, resident in regs (AGPR-friendly)
    s8b bfr[32];
    {
        const unsigned short* pbj = PB + (size_t)jglob * CC + lhi * 8;
        #pragma unroll
        for (int kt = 0; kt < 32; kt++)
            bfr[kt] = *(const s8b*)(pbj + kt * 32);
    }

    // block-wide LSE of slog (start distribution)
    float x0 = slog[th], x1 = slog[th + 256], x2 = slog[th + 512], x3 = slog[th + 768];
    float mw = fmaxf(fmaxf(x0, x1), fmaxf(x2, x3));
    #pragma unroll
    for (int o = 32; o; o >>= 1) mw = fmaxf(mw, __shfl_xor(mw, o));
    __syncthreads();   // toks ready too
    if (l == 0) ps_lds[w] = mw;
    __syncthreads();
    float gm = fmaxf(fmaxf(ps_lds[0], ps_lds[1]), fmaxf(ps_lds[2], ps_lds[3]));
    __syncthreads();
    float e4 = __expf(x0 - gm) + __expf(x1 - gm) + __expf(x2 - gm) + __expf(x3 - gm);
    #pragma unroll
    for (int o = 32; o; o >>= 1) e4 += __shfl_xor(e4, o);
    if (l == 0) ps_lds[w] = e4;
    __syncthreads();
    float slse = gm + __logf(ps_lds[0] + ps_lds[1] + ps_lds[2] + ps_lds[3]);
    __syncthreads();

    // ---- t = 0: v0 = p0 * e0 into vtile, wave0 computes per-n sums ----
    if (th < 64) {
        int jj = blk * 64 + th;
        float p0 = __expf(slog[jj] - slse);
        #pragma unroll
        for (int n = 0; n < 16; n++) {
            float v0 = p0 * bf2f(eprob[(size_t)toks[n * TT] * CC + jj]);
            vtile[n][th] = f2bf(v0);
            float s = v0;
            #pragma unroll
            for (int o = 32; o; o >>= 1) s += __shfl_xor(s, o);
            if (th == 0) wpart[0][n] = s;
        }
    }
    __syncthreads();
    {   // publish slot 0
        int n = th >> 4, u = th & 15;
        unsigned long long val = ((const unsigned long long*)vtile[n])[u];
        __hip_atomic_store(vbuf64 + ((size_t)n * CC + blk * 64) / 4 + u, val,
                           __ATOMIC_RELAXED, __HIP_MEMORY_SCOPE_AGENT);
    }
    if (th < 8) {
        float s0 = wpart[0][2 * th], s1 = wpart[0][2 * th + 1];
        unsigned long long pv = ((unsigned long long)__builtin_bit_cast(unsigned int, s1) << 32)
                              | __builtin_bit_cast(unsigned int, s0);
        __hip_atomic_store(parts64 + blk * 8 + th, pv,
                           __ATOMIC_RELAXED, __HIP_MEMORY_SCOPE_AGENT);
    }

    // ---- main loop ----
    for (int t = 1; t < TT; t++) {
        // parts loads early (collected after MFMA)
        unsigned long long pj = 0;
        unsigned long long* pp = parts64 + (size_t)(t - 1) * 128 + th;
        if (th < 128)
            pj = __hip_atomic_load(pp, __ATOMIC_RELAXED, __HIP_MEMORY_SCOPE_AGENT);

        // emission gather (read-only cached table)
        float epf[4];
        #pragma unroll
        for (int q = 0; q < 4; q++)
            epf[q] = bf2f(eprob[(size_t)toks[(lhi * 4 + q) * TT + t] * CC + jglob]);

        // A-chunks: 64 x 8B atomic loads, then wave-wide sentinel retry
        unsigned long long* ab = vbuf64 + ((size_t)(t - 1) * NN * CC + (size_t)llo * CC) / 4 + lhi * 2;
        unsigned long long a0[32], a1[32];
        #pragma unroll
        for (int kt = 0; kt < 32; kt++) {
            a0[kt] = __hip_atomic_load(ab + kt * 8,     __ATOMIC_RELAXED, __HIP_MEMORY_SCOPE_AGENT);
            a1[kt] = __hip_atomic_load(ab + kt * 8 + 1, __ATOMIC_RELAXED, __HIP_MEMORY_SCOPE_AGENT);
        }
        for (;;) {
            unsigned int m0 = 0u, m1 = 0u;
            #pragma unroll
            for (int kt = 0; kt < 32; kt++) {
                if (a0[kt] == SENT64) m0 |= 1u << kt;
                if (a1[kt] == SENT64) m1 |= 1u << kt;
            }
            if (!__any((m0 | m1) != 0u)) break;
            #pragma unroll
            for (int kt = 0; kt < 32; kt++) {
                if (m0 & (1u << kt))
                    a0[kt] = __hip_atomic_load(ab + kt * 8,     __ATOMIC_ACQUIRE, __HIP_MEMORY_SCOPE_AGENT);
                if (m1 & (1u << kt))
                    a1[kt] = __hip_atomic_load(ab + kt * 8 + 1, __ATOMIC_ACQUIRE, __HIP_MEMORY_SCOPE_AGENT);
            }
        }

        // MFMA chain: 4 independent accumulators
        f32x4 ac0 = {0,0,0,0}, ac1 = {0,0,0,0}, ac2 = {0,0,0,0}, ac3 = {0,0,0,0};
        #pragma unroll
        for (int kt = 0; kt < 32; kt += 4) {
            union { unsigned long long q[2]; s8b v; } U0, U1, U2, U3;
            U0.q[0] = a0[kt];     U0.q[1] = a1[kt];
            U1.q[0] = a0[kt + 1]; U1.q[1] = a1[kt + 1];
            U2.q[0] = a0[kt + 2]; U2.q[1] = a1[kt + 2];
            U3.q[0] = a0[kt + 3]; U3.q[1] = a1[kt + 3];
            ac0 = __builtin_amdgcn_mfma_f32_16x16x32_bf16(U0.v, bfr[kt + 0], ac0, 0, 0, 0);
            ac1 = __builtin_amdgcn_mfma_f32_16x16x32_bf16(U1.v, bfr[kt + 1], ac1, 0, 0, 0);
            ac2 = __builtin_amdgcn_mfma_f32_16x16x32_bf16(U2.v, bfr[kt + 2], ac2, 0, 0, 0);
            ac3 = __builtin_amdgcn_mfma_f32_16x16x32_bf16(U3.v, bfr[kt + 3], ac3, 0, 0, 0);
        }
        f32x4 acc = (ac0 + ac1) + (ac2 + ac3);

        // parts collect (+retry), then per-n scale factors
        if (th < 128) {
            while (pj == SENT64)
                pj = __hip_atomic_load(pp, __ATOMIC_ACQUIRE, __HIP_MEMORY_SCOPE_AGENT);
            ps_lds[2 * th]     = __builtin_bit_cast(float, (unsigned int)(pj & 0xFFFFFFFFu));
            ps_lds[2 * th + 1] = __builtin_bit_cast(float, (unsigned int)(pj >> 32));
        }
        __syncthreads();
        if (th < 16) {
            float S = 0.f;
            #pragma unroll
            for (int b = 0; b < 16; b++) S += ps_lds[b * 16 + th];
            sinv_lds[th] = 1.0f / S;
            if (blk == 0) logacc[th] += __logf(S);
        }
        __syncthreads();

        // epilogue: scale, emit-multiply, per-n partial sums, stage into vtile
        #pragma unroll
        for (int q = 0; q < 4; q++) {
            int nn2 = lhi * 4 + q;   // C/D: row = (lane>>4)*4 + reg, col = lane&15
            float vq = acc[q] * sinv_lds[nn2] * epf[q];
            float sp = vq;
            #pragma unroll
            for (int o = 1; o < 16; o <<= 1) sp += __shfl_xor(sp, o);
            if (llo == 0) wpart[w][nn2] = sp;
            vtile[nn2][w * 16 + llo] = f2bf(vq);
        }
        __syncthreads();

        // publish slot t
        {
            int n = th >> 4, u = th & 15;
            unsigned long long val = ((const unsigned long long*)vtile[n])[u];
            __hip_atomic_store(vbuf64 + ((size_t)t * NN * CC + (size_t)n * CC + blk * 64) / 4 + u, val,
                               __ATOMIC_RELAXED, __HIP_MEMORY_SCOPE_AGENT);
        }
        if (th < 8) {
            float s0 = wpart[0][2*th]   + wpart[1][2*th]   + wpart[2][2*th]   + wpart[3][2*th];
            float s1 = wpart[0][2*th+1] + wpart[1][2*th+1] + wpart[2][2*th+1] + wpart[3][2*th+1];
            unsigned long long pv = ((unsigned long long)__builtin_bit_cast(unsigned int, s1) << 32)
                                  | __builtin_bit_cast(unsigned int, s0);
            __hip_atomic_store(parts64 + (size_t)t * 128 + blk * 8 + th, pv,
                               __ATOMIC_RELAXED, __HIP_MEMORY_SCOPE_AGENT);
        }
    }

    // ---- final: block 0 collects parts[255], folds last S, writes output ----
    if (blk == 0) {
        if (th < 128) {
            unsigned long long* pp = parts64 + (size_t)255 * 128 + th;
            unsigned long long pj = __hip_atomic_load(pp, __ATOMIC_RELAXED, __HIP_MEMORY_SCOPE_AGENT);
            while (pj == SENT64)
                pj = __hip_atomic_load(pp, __ATOMIC_ACQUIRE, __HIP_MEMORY_SCOPE_AGENT);
            ps_lds[2 * th]     = __builtin_bit_cast(float, (unsigned int)(pj & 0xFFFFFFFFu));
            ps_lds[2 * th + 1] = __builtin_bit_cast(float, (unsigned int)(pj >> 32));
        }
        __syncthreads();
        if (th == 0) {
            float total = 0.f;
            for (int n = 0; n < 16; n++) {
                float S = 0.f;
                for (int b = 0; b < 16; b++) S += ps_lds[b * 16 + n];
                total += logacc[n] + __logf(S);
            }
            outp[0] = total;
        }
    }
}

extern "C" void kernel_launch(void* const* d_in, const int* in_sizes, int n_in,
                              void* d_out, int out_size, void* d_ws, size_t ws_size,
                              hipStream_t stream) {
    const int*   text      = (const int*)  d_in[0];
    const float* start_emb = (const float*)d_in[1];
    const float* sw1 = (const float*)d_in[2];
    const float* sb1 = (const float*)d_in[3];
    const float* sw2 = (const float*)d_in[4];
    const float* sb2 = (const float*)d_in[5];
    const float* sw3 = (const float*)d_in[6];
    const float* sb3 = (const float*)d_in[7];
    const float* state_emb = (const float*)d_in[8];
    const float* tw1 = (const float*)d_in[9];
    const float* tb1 = (const float*)d_in[10];
    const float* tw2 = (const float*)d_in[11];
    const float* tb2 = (const float*)d_in[12];
    const float* tw3 = (const float*)d_in[13];
    const float* tb3 = (const float*)d_in[14];
    const float* pre_emb = (const float*)d_in[15];
    const float* ew1 = (const float*)d_in[16];
    const float* eb1 = (const float*)d_in[17];
    const float* ew2 = (const float*)d_in[18];
    const float* eb2 = (const float*)d_in[19];
    const float* ew3 = (const float*)d_in[20];
    const float* eb3 = (const float*)d_in[21];

    char* wsp = (char*)d_ws;
    // layout (bytes):
    //   PB     [0, 2 MiB)
    //   emitT  [2 MiB, 22,577,152)            (VV*CC*2 = 20,480,000)
    //   res_s  [2 MiB, 3 MiB)    \ overlay emitT head: dead before k_emit writes
    //   res_t  [3 MiB, 4 MiB)    /
    //   res_e  [22,577,152, 23,625,728)       (1 MiB; read by k_emit, outside emitT)
    //   slog   [23,625,728, +4 KiB)
    //   epart  [23,633,920, +32 KiB)
    //   lse    [23,666,688, +4 KiB)
    //   parts  [23,674,880, +256 KiB)         sentinel-armed
    //   vbuf   [23 MiB = 24,117,248, 31 MiB)  sentinel-armed (8 MiB)
    unsigned short* PB    = (unsigned short*)(wsp);
    unsigned short* emitT = (unsigned short*)(wsp + ((size_t)2 << 20));
    float* res_s = (float*)(wsp + ((size_t)2 << 20));
    float* res_t = (float*)(wsp + ((size_t)3 << 20));
    float* res_e = (float*)(wsp + 22577152u);
    float* slog  = (float*)(wsp + 23625728u);
    float* epart = (float*)(wsp + 23633920u);
    float* lse   = (float*)(wsp + 23666688u);
    unsigned long long* parts64 = (unsigned long long*)(wsp + 23674880u);
    unsigned long long* vbuf64  = (unsigned long long*)(wsp + ((size_t)23 << 20));
    float* outp  = (float*)d_out;

    if (ws_size < ((size_t)31 << 20)) return;  // leaves poison -> visible failure

    // arm sentinels first (nothing else lives in these regions)
    hipMemsetAsync(vbuf64,  0xFF, (size_t)TT * NN * CC * sizeof(unsigned short), stream);
    hipMemsetAsync(parts64, 0xFF, (size_t)TT * NB * NN * sizeof(float), stream);

    ResArgs3 ra;
    ra.a[0] = { start_emb, sw1, sb1, sw2, sb2, res_s };
    ra.a[1] = { state_emb, tw1, tb1, tw2, tb2, res_t };
    ra.a[2] = { pre_emb,   ew1, eb1, ew2, eb2, res_e };

    hipLaunchKernelGGL(k_res,   dim3(64, 3), dim3(256), 0, stream, ra);
    hipLaunchKernelGGL(k_slog,  dim3(4),     dim3(256), 0, stream, res_s, sw3, sb3, slog);
    hipLaunchKernelGGL(k_pt,    dim3(256),   dim3(256), 0, stream, res_t, tw3, tb3, PB);
    hipLaunchKernelGGL(k_emit,  dim3(256),   dim3(256), 0, stream, res_e, ew3, eb3, emitT, epart);
    hipLaunchKernelGGL(k_lse,   dim3(4),     dim3(256), 0, stream, epart, lse);
    hipLaunchKernelGGL(k_eprob, dim3(5000),  dim3(256), 0, stream, emitT, lse);
    hipLaunchKernelGGL(k_fwd,   dim3(NB),    dim3(256), 0, stream,
                       PB, emitT, slog, text, vbuf64, parts64, outp);
}

// Round 7
// 1120.550 us; speedup vs baseline: 4.5188x; 4.5188x over previous
//
#include <hip/hip_runtime.h>
#include <hip/hip_bf16.h>
#include <cstddef>

#define CC 1024   // states
#define HH 256    // hidden
#define VV 10000  // vocab
#define NN 16     // batch
#define TT 256    // time
#define NB 16     // blocks in k_fwd

typedef __attribute__((ext_vector_type(8))) short s8b;
typedef __attribute__((ext_vector_type(4))) float f32x4;
typedef __attribute__((ext_vector_type(4))) unsigned int u32x4;

__device__ __forceinline__ unsigned short f2bf(float f) {
    unsigned int b = __builtin_bit_cast(unsigned int, f);
    b += 0x7FFFu + ((b >> 16) & 1u);
    return (unsigned short)(b >> 16);
}
__device__ __forceinline__ float bf2f(unsigned short u) {
    return __builtin_bit_cast(float, ((unsigned int)u) << 16);
}

// ---------------- residual MLP: out = relu(relu(x@w1+b1)@w2+b2) + x ----------------
struct ResArgs { const float *x, *w1, *b1, *w2, *b2; float* o; };
struct ResArgs3 { ResArgs a[3]; };

__global__ __launch_bounds__(256) void k_res(ResArgs3 A)
{
    ResArgs R = A.a[blockIdx.y];
    const int r0 = blockIdx.x * 16;
    const int th = threadIdx.x;
    __shared__ float xs[256][24];
    __shared__ float hs[256][24];
    #pragma unroll
    for (int k = 0; k < 16; k++) xs[th][k] = R.x[(size_t)(r0 + k) * HH + th];
    __syncthreads();
    float acc[16];
    float b1v = R.b1[th];
    #pragma unroll
    for (int r = 0; r < 16; r++) acc[r] = b1v;
    for (int h = 0; h < HH; h++) {
        float w = R.w1[(size_t)h * HH + th];
        #pragma unroll
        for (int r = 0; r < 16; r++) acc[r] = fmaf(xs[h][r], w, acc[r]);
    }
    #pragma unroll
    for (int r = 0; r < 16; r++) hs[th][r] = fmaxf(acc[r], 0.f);
    __syncthreads();
    float b2v = R.b2[th];
    #pragma unroll
    for (int r = 0; r < 16; r++) acc[r] = b2v;
    for (int h = 0; h < HH; h++) {
        float w = R.w2[(size_t)h * HH + th];
        #pragma unroll
        for (int r = 0; r < 16; r++) acc[r] = fmaf(hs[h][r], w, acc[r]);
    }
    #pragma unroll
    for (int r = 0; r < 16; r++) {
        size_t idx = (size_t)(r0 + r) * HH + th;
        R.o[idx] = fmaxf(acc[r], 0.f) + R.x[idx];
    }
}

// ---------------- start logits ----------------
__global__ __launch_bounds__(256) void k_slog(const float* __restrict__ res_s,
                                              const float* __restrict__ sw3,
                                              const float* __restrict__ sb3,
                                              float* __restrict__ slog)
{
    __shared__ float wv[256];
    const int th = threadIdx.x;
    const int c = blockIdx.x * 256 + th;
    wv[th] = sw3[th];
    __syncthreads();
    const float* row = res_s + (size_t)c * HH;
    float acc = 0.f;
    for (int h = 0; h < HH; h++) acc = fmaf(row[h], wv[h], acc);
    slog[c] = acc + sb3[0];
}

// ---------------- transition probs, transposed bf16: PB[j][i] = p(j | i) ----------------
__global__ __launch_bounds__(256) void k_pt(const float* __restrict__ res_t,
                                            const float* __restrict__ tw3,
                                            const float* __restrict__ tb3,
                                            unsigned short* __restrict__ PB)
{
    const int r0 = blockIdx.x * 4;
    const int th = threadIdx.x;
    __shared__ float rs[4][256];
    __shared__ float sred[256];
    for (int k = 0; k < 4; k++) rs[k][th] = res_t[(size_t)(r0 + k) * HH + th];
    __syncthreads();
    float acc[4][4];
    #pragma unroll
    for (int r = 0; r < 4; r++)
        #pragma unroll
        for (int q = 0; q < 4; q++) acc[r][q] = tb3[th + q * 256];
    for (int h = 0; h < HH; h++) {
        float w0 = tw3[(size_t)h * CC + th];
        float w1 = tw3[(size_t)h * CC + th + 256];
        float w2 = tw3[(size_t)h * CC + th + 512];
        float w3 = tw3[(size_t)h * CC + th + 768];
        #pragma unroll
        for (int r = 0; r < 4; r++) {
            float xv = rs[r][h];
            acc[r][0] = fmaf(xv, w0, acc[r][0]);
            acc[r][1] = fmaf(xv, w1, acc[r][1]);
            acc[r][2] = fmaf(xv, w2, acc[r][2]);
            acc[r][3] = fmaf(xv, w3, acc[r][3]);
        }
    }
    for (int r = 0; r < 4; r++) {
        float m = fmaxf(fmaxf(acc[r][0], acc[r][1]), fmaxf(acc[r][2], acc[r][3]));
        sred[th] = m; __syncthreads();
        for (int off = 128; off > 0; off >>= 1) { if (th < off) sred[th] = fmaxf(sred[th], sred[th + off]); __syncthreads(); }
        float rm = sred[0]; __syncthreads();
        float ssum = __expf(acc[r][0] - rm) + __expf(acc[r][1] - rm) + __expf(acc[r][2] - rm) + __expf(acc[r][3] - rm);
        sred[th] = ssum; __syncthreads();
        for (int off = 128; off > 0; off >>= 1) { if (th < off) sred[th] += sred[th + off]; __syncthreads(); }
        float inv = 1.0f / sred[0]; __syncthreads();
        #pragma unroll
        for (int q = 0; q < 4; q++) {
            float p = __expf(acc[r][q] - rm) * inv;
            PB[(size_t)(th + q * 256) * CC + (r0 + r)] = f2bf(p);   // [j][i]
        }
    }
}

// ---------------- emission logits bf16 + per-chunk LSE partials ----------------
__global__ __launch_bounds__(256) void k_emit(const float* __restrict__ res_e,
                                              const float* __restrict__ ew3,
                                              const float* __restrict__ eb3,
                                              unsigned short* __restrict__ emitT,
                                              float* __restrict__ epart)
{
    const int ct = blockIdx.x >> 2, jc = blockIdx.x & 3;
    const int c0 = ct * 16, j0 = jc * 2500;
    const int th = threadIdx.x;
    __shared__ float rs[256][24];
    __shared__ float sred[256];
    for (int k = 0; k < 16; k++) rs[th][k] = res_e[(size_t)(c0 + k) * HH + th];
    __syncthreads();
    float lm[16], ls[16];
    #pragma unroll
    for (int c = 0; c < 16; c++) { lm[c] = -1e30f; ls[c] = 0.f; }
    for (int it = 0; it < 10; it++) {
        int jo = it * 256 + th;
        if (jo < 2500) {
            int j = j0 + jo;
            float acc[16];
            float bb = eb3[j];
            #pragma unroll
            for (int c = 0; c < 16; c++) acc[c] = bb;
            for (int h = 0; h < HH; h++) {
                float wv = ew3[(size_t)h * VV + j];
                #pragma unroll
                for (int c = 0; c < 16; c++) acc[c] = fmaf(rs[h][c], wv, acc[c]);
            }
            #pragma unroll
            for (int c = 0; c < 16; c++) {
                emitT[(size_t)j * CC + c0 + c] = f2bf(acc[c]);
                float nm = fmaxf(lm[c], acc[c]);
                ls[c] = ls[c] * __expf(lm[c] - nm) + __expf(acc[c] - nm);
                lm[c] = nm;
            }
        }
    }
    for (int c = 0; c < 16; c++) {
        sred[th] = lm[c]; __syncthreads();
        for (int off = 128; off > 0; off >>= 1) { if (th < off) sred[th] = fmaxf(sred[th], sred[th + off]); __syncthreads(); }
        float gm = sred[0]; __syncthreads();
        sred[th] = (lm[c] > -1e29f) ? ls[c] * __expf(lm[c] - gm) : 0.f;
        __syncthreads();
        for (int off = 128; off > 0; off >>= 1) { if (th < off) sred[th] += sred[th + off]; __syncthreads(); }
        if (th == 0) {
            epart[((size_t)jc * CC + c0 + c) * 2]     = gm;
            epart[((size_t)jc * CC + c0 + c) * 2 + 1] = sred[0];
        }
        __syncthreads();
    }
}

// ---------------- combine epart -> lse[c] ----------------
__global__ __launch_bounds__(256) void k_lse(const float* __restrict__ epart,
                                             float* __restrict__ lse)
{
    int c = blockIdx.x * 256 + threadIdx.x;
    float M = -1e30f, S = 0.f;
    #pragma unroll
    for (int q = 0; q < 4; q++) {
        float m  = epart[((size_t)q * CC + c) * 2];
        float s2 = epart[((size_t)q * CC + c) * 2 + 1];
        float nm = fmaxf(M, m);
        S = S * __expf(M - nm) + s2 * __expf(m - nm);
        M = nm;
    }
    lse[c] = M + __logf(S);
}

// ---------------- in-place: emitT logits -> eprob = exp(logit - lse[c]) ----------------
__global__ __launch_bounds__(256) void k_eprob(unsigned short* __restrict__ emitT,
                                               const float* __restrict__ lse)
{
    __shared__ float ls[1024];
    const int th = threadIdx.x;
    for (int i = th; i < 1024; i += 256) ls[i] = lse[i];
    __syncthreads();
    size_t base = ((size_t)blockIdx.x * 256 + th) * 8;
    int c0 = (int)(base & 1023);
    s8b v = *(const s8b*)(emitT + base);
    unsigned short o[8];
    #pragma unroll
    for (int e = 0; e < 8; e++)
        o[e] = f2bf(__expf(bf2f((unsigned short)v[e]) - ls[c0 + e]));
    s8b ov;
    #pragma unroll
    for (int e = 0; e < 8; e++) ov[e] = (short)o[e];
    *(s8b*)(emitT + base) = ov;
}

// load 8x16B coherent chunks of v[tslot] (this thread's share), sentinel-retry,
// then stage into swizzled LDS. Loads+waitcnt kept adjacent (no pipelining across
// other code) so regalloc can't spill pending asm outputs.
__device__ __forceinline__ void load_stage(const unsigned short* vbuf_t, int th, char* vl)
{
    const unsigned short* sb = vbuf_t + th * 8;
    s8b ch[8];
    #pragma unroll
    for (int c = 0; c < 8; c++)
        asm volatile("global_load_dwordx4 %0, %1, off sc0 sc1"
                     : "=v"(ch[c]) : "v"(sb + c * 2048));
    asm volatile("s_waitcnt vmcnt(0)" ::: "memory");
    __builtin_amdgcn_sched_barrier(0);
    for (;;) {
        unsigned int miss = 0u;
        #pragma unroll
        for (int c = 0; c < 8; c++) {
            u32x4 d = __builtin_bit_cast(u32x4, ch[c]);
            if (d[0] == 0xFFFFFFFFu || d[1] == 0xFFFFFFFFu ||
                d[2] == 0xFFFFFFFFu || d[3] == 0xFFFFFFFFu) miss |= 1u << c;
        }
        if (miss == 0u) break;
        #pragma unroll
        for (int c = 0; c < 8; c++)
            if (miss & (1u << c))
                asm volatile("global_load_dwordx4 %0, %1, off sc0 sc1"
                             : "=v"(ch[c]) : "v"(sb + c * 2048));
        asm volatile("s_waitcnt vmcnt(0)" ::: "memory");
        __builtin_amdgcn_sched_barrier(0);
    }
    #pragma unroll
    for (int c = 0; c < 8; c++) {
        int ow = c * 4096 + th * 16;
        *(s8b*)(vl + (ow ^ (((ow >> 11) & 7) << 4))) = ch[c];
    }
}

// ---------------- forward scan: sentinel data-poll + LDS broadcast + ones-MFMA ----------------
__global__ void __launch_bounds__(256, 1) k_fwd(
    const unsigned short* __restrict__ PB,    // [1024 j][1024 i] bf16
    const unsigned short* __restrict__ eprob, // [V][1024 c] bf16
    const float* __restrict__ slog,
    const int* __restrict__ text,
    unsigned short* vbuf,                     // [TT][NN][CC] bf16, sentinel-armed
    float* __restrict__ outp)
{
    const int blk = blockIdx.x;
    const int th = threadIdx.x;
    const int w = th >> 6, l = th & 63;
    const int lhi = l >> 4, llo = l & 15;
    const int jglob = blk * 64 + w * 16 + llo;

    __shared__ int toks[NN * TT];                              // 16 KB
    __shared__ __align__(16) unsigned short vlds[NN * CC];     // 32 KB staged v
    __shared__ __align__(16) unsigned short vtile[16][72];     // publish staging (padded)
    __shared__ float swk[4];
    __shared__ float fin[16];

    for (int i = th; i < NN * TT; i += 256) toks[i] = text[i];

    // B fragments: wave's 16 j-columns, K=1024 -> 32 tiles resident in regs
    s8b bfr[32];
    {
        const unsigned short* pbj = PB + (size_t)jglob * CC + lhi * 8;
        #pragma unroll
        for (int kt = 0; kt < 32; kt++)
            bfr[kt] = *(const s8b*)(pbj + kt * 32);
    }
    s8b ones;
    #pragma unroll
    for (int e = 0; e < 8; e++) ones[e] = (short)0x3F80;   // bf16 1.0

    // block-wide LSE of slog
    float x0 = slog[th], x1 = slog[th + 256], x2 = slog[th + 512], x3 = slog[th + 768];
    float mw = fmaxf(fmaxf(x0, x1), fmaxf(x2, x3));
    #pragma unroll
    for (int o = 32; o; o >>= 1) mw = fmaxf(mw, __shfl_xor(mw, o));
    __syncthreads();   // toks ready
    if (l == 0) swk[w] = mw;
    __syncthreads();
    float gm = fmaxf(fmaxf(swk[0], swk[1]), fmaxf(swk[2], swk[3]));
    __syncthreads();
    float e4 = __expf(x0 - gm) + __expf(x1 - gm) + __expf(x2 - gm) + __expf(x3 - gm);
    #pragma unroll
    for (int o = 32; o; o >>= 1) e4 += __shfl_xor(e4, o);
    if (l == 0) swk[w] = e4;
    __syncthreads();
    float slse = gm + __logf(swk[0] + swk[1] + swk[2] + swk[3]);
    __syncthreads();

    // ---- t = 0: v0 = p0 * e0 for this block's 64 states, publish canonical chunks ----
    if (th < 64) {
        int jj = blk * 64 + th;
        float p0 = __expf(slog[jj] - slse);
        #pragma unroll
        for (int n = 0; n < 16; n++)
            vtile[n][th] = f2bf(p0 * bf2f(eprob[(size_t)toks[n * TT] * CC + jj]));
    }
    __syncthreads();
    if (th < 128) {
        int n = th >> 3, seg = th & 7;
        s8b val = *(const s8b*)&vtile[n][seg * 8];
        unsigned short* dst = vbuf + (size_t)n * CC + blk * 64 + seg * 8;
        asm volatile("global_store_dwordx4 %0, %1, off sc0 sc1" :: "v"(dst), "v"(val) : "memory");
    }

    float logaccq[4] = {0.f, 0.f, 0.f, 0.f};
    char* vl = (char*)vlds;
    const int rkey = (llo & 7) << 4;
    const int rbase = llo * 2048 + lhi * 16;

    for (int t = 1; t < TT; t++) {
        // emission gather for this step (cached, read-only)
        float epf[4];
        #pragma unroll
        for (int q = 0; q < 4; q++)
            epf[q] = bf2f(eprob[(size_t)toks[(lhi * 4 + q) * TT + t] * CC + jglob]);

        // coherent load + sentinel retry + LDS stage of full v[t-1]
        load_stage(vbuf + (size_t)(t - 1) * (NN * CC), th, vl);
        __syncthreads();

        // MFMA: main chain (4-deep) + ones-chain (2-deep) for row sums S_n
        f32x4 ac0 = {0,0,0,0}, ac1 = {0,0,0,0}, ac2 = {0,0,0,0}, ac3 = {0,0,0,0};
        f32x4 ao0 = {0,0,0,0}, ao1 = {0,0,0,0};
        #pragma unroll
        for (int kt = 0; kt < 32; kt += 4) {
            s8b a0 = *(const s8b*)(vl + ((rbase + (kt + 0) * 64) ^ rkey));
            s8b a1 = *(const s8b*)(vl + ((rbase + (kt + 1) * 64) ^ rkey));
            s8b a2 = *(const s8b*)(vl + ((rbase + (kt + 2) * 64) ^ rkey));
            s8b a3 = *(const s8b*)(vl + ((rbase + (kt + 3) * 64) ^ rkey));
            ac0 = __builtin_amdgcn_mfma_f32_16x16x32_bf16(a0, bfr[kt + 0], ac0, 0, 0, 0);
            ao0 = __builtin_amdgcn_mfma_f32_16x16x32_bf16(a0, ones,        ao0, 0, 0, 0);
            ac1 = __builtin_amdgcn_mfma_f32_16x16x32_bf16(a1, bfr[kt + 1], ac1, 0, 0, 0);
            ao1 = __builtin_amdgcn_mfma_f32_16x16x32_bf16(a1, ones,        ao1, 0, 0, 0);
            ac2 = __builtin_amdgcn_mfma_f32_16x16x32_bf16(a2, bfr[kt + 2], ac2, 0, 0, 0);
            ao0 = __builtin_amdgcn_mfma_f32_16x16x32_bf16(a2, ones,        ao0, 0, 0, 0);
            ac3 = __builtin_amdgcn_mfma_f32_16x16x32_bf16(a3, bfr[kt + 3], ac3, 0, 0, 0);
            ao1 = __builtin_amdgcn_mfma_f32_16x16x32_bf16(a3, ones,        ao1, 0, 0, 0);
        }
        f32x4 acc = (ac0 + ac1) + (ac2 + ac3);
        f32x4 aco = ao0 + ao1;   // aco[q] = S_{n=lhi*4+q} (all columns identical)

        // epilogue: scale by 1/S, emission multiply, stage for publish
        #pragma unroll
        for (int q = 0; q < 4; q++) {
            float S = aco[q];
            logaccq[q] += __logf(S);
            float vq = acc[q] * (1.0f / S) * epf[q];
            vtile[lhi * 4 + q][w * 16 + llo] = f2bf(vq);
        }
        __syncthreads();

        // publish: 128 lanes store 16B canonical chunks
        if (th < 128) {
            int n = th >> 3, seg = th & 7;
            s8b val = *(const s8b*)&vtile[n][seg * 8];
            unsigned short* dst = vbuf + (size_t)t * (NN * CC) + (size_t)n * CC + blk * 64 + seg * 8;
            asm volatile("global_store_dwordx4 %0, %1, off sc0 sc1" :: "v"(dst), "v"(val) : "memory");
        }
    }

    // ---- final: block 0 loads v[255], computes S_255 via ones-MFMA, writes output ----
    if (blk == 0) {
        load_stage(vbuf + (size_t)255 * (NN * CC), th, vl);
        __syncthreads();
        f32x4 ao0 = {0,0,0,0}, ao1 = {0,0,0,0};
        #pragma unroll
        for (int kt = 0; kt < 32; kt += 2) {
            s8b a0 = *(const s8b*)(vl + ((rbase + (kt + 0) * 64) ^ rkey));
            s8b a1 = *(const s8b*)(vl + ((rbase + (kt + 1) * 64) ^ rkey));
            ao0 = __builtin_amdgcn_mfma_f32_16x16x32_bf16(a0, ones, ao0, 0, 0, 0);
            ao1 = __builtin_amdgcn_mfma_f32_16x16x32_bf16(a1, ones, ao1, 0, 0, 0);
        }
        f32x4 acoF = ao0 + ao1;
        if (w == 0 && llo == 0) {
            #pragma unroll
            for (int q = 0; q < 4; q++)
                fin[lhi * 4 + q] = logaccq[q] + __logf(acoF[q]);
        }
        __syncthreads();
        if (th == 0) {
            float tot = 0.f;
            for (int n = 0; n < 16; n++) tot += fin[n];
            outp[0] = tot;
        }
    }
}

extern "C" void kernel_launch(void* const* d_in, const int* in_sizes, int n_in,
                              void* d_out, int out_size, void* d_ws, size_t ws_size,
                              hipStream_t stream) {
    const int*   text      = (const int*)  d_in[0];
    const float* start_emb = (const float*)d_in[1];
    const float* sw1 = (const float*)d_in[2];
    const float* sb1 = (const float*)d_in[3];
    const float* sw2 = (const float*)d_in[4];
    const float* sb2 = (const float*)d_in[5];
    const float* sw3 = (const float*)d_in[6];
    const float* sb3 = (const float*)d_in[7];
    const float* state_emb = (const float*)d_in[8];
    const float* tw1 = (const float*)d_in[9];
    const float* tb1 = (const float*)d_in[10];
    const float* tw2 = (const float*)d_in[11];
    const float* tb2 = (const float*)d_in[12];
    const float* tw3 = (const float*)d_in[13];
    const float* tb3 = (const float*)d_in[14];
    const float* pre_emb = (const float*)d_in[15];
    const float* ew1 = (const float*)d_in[16];
    const float* eb1 = (const float*)d_in[17];
    const float* ew2 = (const float*)d_in[18];
    const float* eb2 = (const float*)d_in[19];
    const float* ew3 = (const float*)d_in[20];
    const float* eb3 = (const float*)d_in[21];

    char* wsp = (char*)d_ws;
    // layout (bytes):
    //   PB     [0, 2 MiB)
    //   emitT  [2 MiB, 22,577,152)            (VV*CC*2 = 20,480,000)
    //   res_s  [2 MiB, 3 MiB)    \ overlay emitT head: dead before k_emit writes
    //   res_t  [3 MiB, 4 MiB)    /
    //   res_e  [22,577,152, 23,625,728)       (read by k_emit, outside emitT)
    //   slog   [23,625,728, +4 KiB)
    //   epart  [23,633,920, +32 KiB)
    //   lse    [23,666,688, +4 KiB)
    //   vbuf   [23 MiB = 24,117,248, 31 MiB)  sentinel-armed (8 MiB)
    unsigned short* PB    = (unsigned short*)(wsp);
    unsigned short* emitT = (unsigned short*)(wsp + ((size_t)2 << 20));
    float* res_s = (float*)(wsp + ((size_t)2 << 20));
    float* res_t = (float*)(wsp + ((size_t)3 << 20));
    float* res_e = (float*)(wsp + 22577152u);
    float* slog  = (float*)(wsp + 23625728u);
    float* epart = (float*)(wsp + 23633920u);
    float* lse   = (float*)(wsp + 23666688u);
    unsigned short* vbuf = (unsigned short*)(wsp + ((size_t)23 << 20));
    float* outp  = (float*)d_out;

    if (ws_size < ((size_t)31 << 20)) return;  // leaves poison -> visible failure

    // arm sentinels (nothing else lives in this region)
    hipMemsetAsync(vbuf, 0xFF, (size_t)TT * NN * CC * sizeof(unsigned short), stream);

    ResArgs3 ra;
    ra.a[0] = { start_emb, sw1, sb1, sw2, sb2, res_s };
    ra.a[1] = { state_emb, tw1, tb1, tw2, tb2, res_t };
    ra.a[2] = { pre_emb,   ew1, eb1, ew2, eb2, res_e };

    hipLaunchKernelGGL(k_res,   dim3(64, 3), dim3(256), 0, stream, ra);
    hipLaunchKernelGGL(k_slog,  dim3(4),     dim3(256), 0, stream, res_s, sw3, sb3, slog);
    hipLaunchKernelGGL(k_pt,    dim3(256),   dim3(256), 0, stream, res_t, tw3, tb3, PB);
    hipLaunchKernelGGL(k_emit,  dim3(256),   dim3(256), 0, stream, res_e, ew3, eb3, emitT, epart);
    hipLaunchKernelGGL(k_lse,   dim3(4),     dim3(256), 0, stream, epart, lse);
    hipLaunchKernelGGL(k_eprob, dim3(5000),  dim3(256), 0, stream, emitT, lse);
    hipLaunchKernelGGL(k_fwd,   dim3(NB),    dim3(256), 0, stream,
                       PB, emitT, slog, text, vbuf, outp);
}

// Round 8
// 979.339 us; speedup vs baseline: 5.1703x; 1.1442x over previous
//
#include <hip/hip_runtime.h>
#include <hip/hip_bf16.h>
#include <cstddef>

#define CC 1024   // states
#define HH 256    // hidden
#define VV 10000  // vocab
#define NN 16     // batch
#define TT 256    // time
#define NB 16     // blocks in k_fwd
#define NVB 40    // v-tiles in k_emitg (40 x 256 covers 10240 >= 10000)

typedef __attribute__((ext_vector_type(8))) short s8b;
typedef __attribute__((ext_vector_type(4))) float f32x4;
typedef __attribute__((ext_vector_type(4))) unsigned int u32x4;

__device__ __forceinline__ unsigned short f2bf(float f) {
    unsigned int b = __builtin_bit_cast(unsigned int, f);
    b += 0x7FFFu + ((b >> 16) & 1u);
    return (unsigned short)(b >> 16);
}
__device__ __forceinline__ float bf2f(unsigned short u) {
    return __builtin_bit_cast(float, ((unsigned int)u) << 16);
}

// ---------------- residual MLP: out = relu(relu(x@w1+b1)@w2+b2) + x ----------------
struct ResArgs { const float *x, *w1, *b1, *w2, *b2; float* o; };
struct ResArgs3 { ResArgs a[3]; };

__global__ __launch_bounds__(256) void k_res(ResArgs3 A)
{
    ResArgs R = A.a[blockIdx.y];
    const int r0 = blockIdx.x * 16;
    const int th = threadIdx.x;
    __shared__ float xs[256][24];
    __shared__ float hs[256][24];
    #pragma unroll
    for (int k = 0; k < 16; k++) xs[th][k] = R.x[(size_t)(r0 + k) * HH + th];
    __syncthreads();
    float acc[16];
    float b1v = R.b1[th];
    #pragma unroll
    for (int r = 0; r < 16; r++) acc[r] = b1v;
    for (int h = 0; h < HH; h++) {
        float w = R.w1[(size_t)h * HH + th];
        #pragma unroll
        for (int r = 0; r < 16; r++) acc[r] = fmaf(xs[h][r], w, acc[r]);
    }
    #pragma unroll
    for (int r = 0; r < 16; r++) hs[th][r] = fmaxf(acc[r], 0.f);
    __syncthreads();
    float b2v = R.b2[th];
    #pragma unroll
    for (int r = 0; r < 16; r++) acc[r] = b2v;
    for (int h = 0; h < HH; h++) {
        float w = R.w2[(size_t)h * HH + th];
        #pragma unroll
        for (int r = 0; r < 16; r++) acc[r] = fmaf(hs[h][r], w, acc[r]);
    }
    #pragma unroll
    for (int r = 0; r < 16; r++) {
        size_t idx = (size_t)(r0 + r) * HH + th;
        R.o[idx] = fmaxf(acc[r], 0.f) + R.x[idx];
    }
}

// ---------------- start logits ----------------
__global__ __launch_bounds__(256) void k_slog(const float* __restrict__ res_s,
                                              const float* __restrict__ sw3,
                                              const float* __restrict__ sb3,
                                              float* __restrict__ slog)
{
    __shared__ float wv[256];
    const int th = threadIdx.x;
    const int c = blockIdx.x * 256 + th;
    wv[th] = sw3[th];
    __syncthreads();
    const float* row = res_s + (size_t)c * HH;
    float acc = 0.f;
    for (int h = 0; h < HH; h++) acc = fmaf(row[h], wv[h], acc);
    slog[c] = acc + sb3[0];
}

// ---------------- transition probs, transposed bf16: PB[j][i] = p(j | i) ----------------
__global__ __launch_bounds__(256) void k_pt(const float* __restrict__ res_t,
                                            const float* __restrict__ tw3,
                                            const float* __restrict__ tb3,
                                            unsigned short* __restrict__ PB)
{
    const int r0 = blockIdx.x * 4;
    const int th = threadIdx.x;
    __shared__ float rs[4][256];
    __shared__ float sred[256];
    for (int k = 0; k < 4; k++) rs[k][th] = res_t[(size_t)(r0 + k) * HH + th];
    __syncthreads();
    float acc[4][4];
    #pragma unroll
    for (int r = 0; r < 4; r++)
        #pragma unroll
        for (int q = 0; q < 4; q++) acc[r][q] = tb3[th + q * 256];
    for (int h = 0; h < HH; h++) {
        float w0 = tw3[(size_t)h * CC + th];
        float w1 = tw3[(size_t)h * CC + th + 256];
        float w2 = tw3[(size_t)h * CC + th + 512];
        float w3 = tw3[(size_t)h * CC + th + 768];
        #pragma unroll
        for (int r = 0; r < 4; r++) {
            float xv = rs[r][h];
            acc[r][0] = fmaf(xv, w0, acc[r][0]);
            acc[r][1] = fmaf(xv, w1, acc[r][1]);
            acc[r][2] = fmaf(xv, w2, acc[r][2]);
            acc[r][3] = fmaf(xv, w3, acc[r][3]);
        }
    }
    for (int r = 0; r < 4; r++) {
        float m = fmaxf(fmaxf(acc[r][0], acc[r][1]), fmaxf(acc[r][2], acc[r][3]));
        sred[th] = m; __syncthreads();
        for (int off = 128; off > 0; off >>= 1) { if (th < off) sred[th] = fmaxf(sred[th], sred[th + off]); __syncthreads(); }
        float rm = sred[0]; __syncthreads();
        float ssum = __expf(acc[r][0] - rm) + __expf(acc[r][1] - rm) + __expf(acc[r][2] - rm) + __expf(acc[r][3] - rm);
        sred[th] = ssum; __syncthreads();
        for (int off = 128; off > 0; off >>= 1) { if (th < off) sred[th] += sred[th + off]; __syncthreads(); }
        float inv = 1.0f / sred[0]; __syncthreads();
        #pragma unroll
        for (int q = 0; q < 4; q++) {
            float p = __expf(acc[r][q] - rm) * inv;
            PB[(size_t)(th + q * 256) * CC + (r0 + r)] = f2bf(p);   // [j][i]
        }
    }
}

// ---------------- emission logits via MFMA GEMM + fused LSE partials ----------------
// D[v][c] = ew3^T @ res_e^T : A-side rows = v (ewT panel), B-side cols = c (res panel).
// Block: 64 c x 256 v (4 rounds of 64 v), K=256 in LDS. 4 waves = 2x2 (wv, wc).
// epart2[vb][c] = {max, sumexp} over the block's 256 v.
__global__ __launch_bounds__(256) void k_emitg(const float* __restrict__ res_e,
                                               const float* __restrict__ ew3,
                                               const float* __restrict__ eb3,
                                               unsigned short* __restrict__ emitT,
                                               float* __restrict__ epart2)
{
    const int vb = blockIdx.x, c0 = blockIdx.y * 64;
    const int th = threadIdx.x;
    const int w = th >> 6, l = th & 63;
    const int lhi = l >> 4, llo = l & 15;
    const int wv = w & 1, wc = w >> 1;

    __shared__ __align__(16) unsigned short ewT[64 * 256];   // 32 KB, [v-loc][h] swizzled
    __shared__ __align__(16) unsigned short rsb[64 * 256];   // 32 KB, [c-loc][h] swizzled
    __shared__ float ebl[64];
    __shared__ float wlse[4][2][16][2];

    // stage res_e panel (c0..c0+64, all h) -> bf16 swizzled
    {
        char* base = (char*)rsb;
        #pragma unroll
        for (int i = 0; i < 8; i++) {
            int g = i * 2048 + th * 8;
            int row = g >> 8, h0 = g & 255;
            const float* src = res_e + (size_t)(c0 + row) * HH + h0;
            float4 f0 = *(const float4*)(src);
            float4 f1 = *(const float4*)(src + 4);
            s8b pk;
            pk[0] = (short)f2bf(f0.x); pk[1] = (short)f2bf(f0.y);
            pk[2] = (short)f2bf(f0.z); pk[3] = (short)f2bf(f0.w);
            pk[4] = (short)f2bf(f1.x); pk[5] = (short)f2bf(f1.y);
            pk[6] = (short)f2bf(f1.z); pk[7] = (short)f2bf(f1.w);
            *(s8b*)(base + row * 512 + ((h0 * 2) ^ ((row & 7) << 4))) = pk;
        }
    }

    float rM[2] = {-1e30f, -1e30f}, rS[2] = {0.f, 0.f};   // running LSE per merger thread... (only th<64 uses)

    for (int r = 0; r < 4; r++) {
        const int v0r = vb * 256 + r * 64;
        __syncthreads();   // protect ewT/wlse reuse
        // stage ewT chunk: [64 v][256 h] transposed from ew3[h][v], swizzled
        {
            int tv = th & 63;
            char* base = (char*)ewT;
            int rowoff = tv * 512;
            int key = (tv & 7) << 4;
            int vglob = v0r + tv;
            bool valid = vglob < VV;
            #pragma unroll 8
            for (int i = 0; i < 64; i++) {
                int h = (th >> 6) + i * 4;
                float x = valid ? ew3[(size_t)h * VV + vglob] : 0.f;
                *(unsigned short*)(base + rowoff + ((h * 2) ^ key)) = f2bf(x);
            }
        }
        if (th < 64) ebl[th] = (v0r + th < VV) ? eb3[v0r + th] : 0.f;
        __syncthreads();

        // MFMA: acc[s][u] over 8 k-tiles
        f32x4 acc[2][2] = {{{0,0,0,0},{0,0,0,0}},{{0,0,0,0},{0,0,0,0}}};
        const char* ea = (const char*)ewT;
        const char* rb = (const char*)rsb;
        const int arow0 = wv * 32 + llo, arow1 = wv * 32 + 16 + llo;
        const int brow0 = wc * 32 + llo, brow1 = wc * 32 + 16 + llo;
        const int akey0 = (arow0 & 7) << 4, akey1 = akey0;   // rows differ by 16 -> same &7
        const int bkey0 = (brow0 & 7) << 4;
        #pragma unroll
        for (int kt = 0; kt < 8; kt++) {
            int off = kt * 64 + lhi * 16;
            s8b a0 = *(const s8b*)(ea + arow0 * 512 + (off ^ akey0));
            s8b a1 = *(const s8b*)(ea + arow1 * 512 + (off ^ akey1));
            s8b b0 = *(const s8b*)(rb + brow0 * 512 + (off ^ bkey0));
            s8b b1 = *(const s8b*)(rb + brow1 * 512 + (off ^ bkey0));
            acc[0][0] = __builtin_amdgcn_mfma_f32_16x16x32_bf16(a0, b0, acc[0][0], 0, 0, 0);
            acc[0][1] = __builtin_amdgcn_mfma_f32_16x16x32_bf16(a0, b1, acc[0][1], 0, 0, 0);
            acc[1][0] = __builtin_amdgcn_mfma_f32_16x16x32_bf16(a1, b0, acc[1][0], 0, 0, 0);
            acc[1][1] = __builtin_amdgcn_mfma_f32_16x16x32_bf16(a1, b1, acc[1][1], 0, 0, 0);
        }

        // epilogue: bias, store bf16 logits, per-(u) LSE over this wave's 32 v
        float um[2] = {-1e30f, -1e30f}, us[2] = {0.f, 0.f};
        #pragma unroll
        for (int u = 0; u < 2; u++) {
            float vals[8];
            #pragma unroll
            for (int s = 0; s < 2; s++) {
                #pragma unroll
                for (int q = 0; q < 4; q++) {
                    int vloc = wv * 32 + s * 16 + lhi * 4 + q;
                    int vglob = v0r + vloc;
                    float logit = acc[s][u][q] + ebl[vloc];
                    bool valid = vglob < VV;
                    if (valid)
                        emitT[(size_t)vglob * CC + (c0 + wc * 32 + u * 16 + llo)] = f2bf(logit);
                    vals[s * 4 + q] = valid ? logit : -1e30f;
                }
            }
            float m = vals[0];
            #pragma unroll
            for (int e = 1; e < 8; e++) m = fmaxf(m, vals[e]);
            float ss = 0.f;
            #pragma unroll
            for (int e = 0; e < 8; e++) ss += __expf(vals[e] - m);
            // reduce over lhi groups (lanes l, l^16, l^32, l^48)
            #pragma unroll
            for (int o = 16; o < 64; o <<= 1) {
                float m2 = __shfl_xor(m, o);
                float s2 = __shfl_xor(ss, o);
                float nm = fmaxf(m, m2);
                ss = ss * __expf(m - nm) + s2 * __expf(m2 - nm);
                m = nm;
            }
            um[u] = m; us[u] = ss;
        }
        if (l < 16) {
            #pragma unroll
            for (int u = 0; u < 2; u++) {
                wlse[w][u][l][0] = um[u];
                wlse[w][u][l][1] = us[u];
            }
        }
        __syncthreads();
        if (th < 64) {   // merger: c-loc = th = wc2*32 + u2*16 + llo2
            int wc2 = th >> 5, u2 = (th >> 4) & 1, ll2 = th & 15;
            float m1 = wlse[2 * wc2][u2][ll2][0], s1 = wlse[2 * wc2][u2][ll2][1];
            float m2 = wlse[2 * wc2 + 1][u2][ll2][0], s2 = wlse[2 * wc2 + 1][u2][ll2][1];
            float nm = fmaxf(m1, m2);
            float ns = s1 * __expf(m1 - nm) + s2 * __expf(m2 - nm);
            float om = rM[0], os = rS[0];
            float fm = fmaxf(om, nm);
            rS[0] = os * __expf(om - fm) + ns * __expf(nm - fm);
            rM[0] = fm;
        }
    }
    if (th < 64) {
        epart2[((size_t)vb * CC + c0 + th) * 2]     = rM[0];
        epart2[((size_t)vb * CC + c0 + th) * 2 + 1] = rS[0];
    }
}

// ---------------- combine epart2 -> lse[c] ----------------
__global__ __launch_bounds__(256) void k_lse(const float* __restrict__ epart2,
                                             float* __restrict__ lse)
{
    int c = blockIdx.x * 256 + threadIdx.x;
    float M = -1e30f, S = 0.f;
    for (int vb = 0; vb < NVB; vb++) {
        float m  = epart2[((size_t)vb * CC + c) * 2];
        float s2 = epart2[((size_t)vb * CC + c) * 2 + 1];
        float nm = fmaxf(M, m);
        S = S * __expf(M - nm) + s2 * __expf(m - nm);
        M = nm;
    }
    lse[c] = M + __logf(S);
}

// ---------------- in-place: emitT logits -> eprob = exp(logit - lse[c]) ----------------
__global__ __launch_bounds__(256) void k_eprob(unsigned short* __restrict__ emitT,
                                               const float* __restrict__ lse)
{
    __shared__ float ls[1024];
    const int th = threadIdx.x;
    for (int i = th; i < 1024; i += 256) ls[i] = lse[i];
    __syncthreads();
    size_t base = ((size_t)blockIdx.x * 256 + th) * 8;
    int c0 = (int)(base & 1023);
    s8b v = *(const s8b*)(emitT + base);
    unsigned short o[8];
    #pragma unroll
    for (int e = 0; e < 8; e++)
        o[e] = f2bf(__expf(bf2f((unsigned short)v[e]) - ls[c0 + e]));
    s8b ov;
    #pragma unroll
    for (int e = 0; e < 8; e++) ov[e] = (short)o[e];
    *(s8b*)(emitT + base) = ov;
}

// load 8x16B coherent chunks of v[tslot] (this thread's share), sentinel-retry,
// then stage into swizzled LDS. Loads+waitcnt kept adjacent (no pipelining across
// other code) so regalloc can't spill pending asm outputs.
__device__ __forceinline__ void load_stage(const unsigned short* vbuf_t, int th, char* vl)
{
    const unsigned short* sb = vbuf_t + th * 8;
    s8b ch[8];
    #pragma unroll
    for (int c = 0; c < 8; c++)
        asm volatile("global_load_dwordx4 %0, %1, off sc0 sc1"
                     : "=v"(ch[c]) : "v"(sb + c * 2048));
    asm volatile("s_waitcnt vmcnt(0)" ::: "memory");
    __builtin_amdgcn_sched_barrier(0);
    for (;;) {
        unsigned int miss = 0u;
        #pragma unroll
        for (int c = 0; c < 8; c++) {
            u32x4 d = __builtin_bit_cast(u32x4, ch[c]);
            if (d[0] == 0xFFFFFFFFu || d[1] == 0xFFFFFFFFu ||
                d[2] == 0xFFFFFFFFu || d[3] == 0xFFFFFFFFu) miss |= 1u << c;
        }
        if (miss == 0u) break;
        #pragma unroll
        for (int c = 0; c < 8; c++)
            if (miss & (1u << c))
                asm volatile("global_load_dwordx4 %0, %1, off sc0 sc1"
                             : "=v"(ch[c]) : "v"(sb + c * 2048));
        asm volatile("s_waitcnt vmcnt(0)" ::: "memory");
        __builtin_amdgcn_sched_barrier(0);
    }
    #pragma unroll
    for (int c = 0; c < 8; c++) {
        int ow = c * 4096 + th * 16;
        *(s8b*)(vl + (ow ^ (((ow >> 11) & 7) << 4))) = ch[c];
    }
}

// ---------------- forward scan: sentinel data-poll + LDS broadcast + ones-MFMA ----------------
__global__ void __launch_bounds__(256, 1) k_fwd(
    const unsigned short* __restrict__ PB,    // [1024 j][1024 i] bf16
    const unsigned short* __restrict__ eprob, // [V][1024 c] bf16
    const float* __restrict__ slog,
    const int* __restrict__ text,
    unsigned short* vbuf,                     // [TT][NN][CC] bf16, sentinel-armed
    float* __restrict__ outp)
{
    const int blk = blockIdx.x;
    const int th = threadIdx.x;
    const int w = th >> 6, l = th & 63;
    const int lhi = l >> 4, llo = l & 15;
    const int jglob = blk * 64 + w * 16 + llo;

    __shared__ int toks[NN * TT];                              // 16 KB
    __shared__ __align__(16) unsigned short vlds[NN * CC];     // 32 KB staged v
    __shared__ __align__(16) unsigned short vtile[16][72];     // publish staging (padded)
    __shared__ float swk[4];
    __shared__ float fin[16];

    for (int i = th; i < NN * TT; i += 256) toks[i] = text[i];

    // B fragments: wave's 16 j-columns, K=1024 -> 32 tiles resident in regs
    s8b bfr[32];
    {
        const unsigned short* pbj = PB + (size_t)jglob * CC + lhi * 8;
        #pragma unroll
        for (int kt = 0; kt < 32; kt++)
            bfr[kt] = *(const s8b*)(pbj + kt * 32);
    }
    s8b ones;
    #pragma unroll
    for (int e = 0; e < 8; e++) ones[e] = (short)0x3F80;   // bf16 1.0

    // block-wide LSE of slog
    float x0 = slog[th], x1 = slog[th + 256], x2 = slog[th + 512], x3 = slog[th + 768];
    float mw = fmaxf(fmaxf(x0, x1), fmaxf(x2, x3));
    #pragma unroll
    for (int o = 32; o; o >>= 1) mw = fmaxf(mw, __shfl_xor(mw, o));
    __syncthreads();   // toks ready
    if (l == 0) swk[w] = mw;
    __syncthreads();
    float gm = fmaxf(fmaxf(swk[0], swk[1]), fmaxf(swk[2], swk[3]));
    __syncthreads();
    float e4 = __expf(x0 - gm) + __expf(x1 - gm) + __expf(x2 - gm) + __expf(x3 - gm);
    #pragma unroll
    for (int o = 32; o; o >>= 1) e4 += __shfl_xor(e4, o);
    if (l == 0) swk[w] = e4;
    __syncthreads();
    float slse = gm + __logf(swk[0] + swk[1] + swk[2] + swk[3]);
    __syncthreads();

    // ---- t = 0: v0 = p0 * e0 for this block's 64 states, publish canonical chunks ----
    if (th < 64) {
        int jj = blk * 64 + th;
        float p0 = __expf(slog[jj] - slse);
        #pragma unroll
        for (int n = 0; n < 16; n++)
            vtile[n][th] = f2bf(p0 * bf2f(eprob[(size_t)toks[n * TT] * CC + jj]));
    }
    __syncthreads();
    if (th < 128) {
        int n = th >> 3, seg = th & 7;
        s8b val = *(const s8b*)&vtile[n][seg * 8];
        unsigned short* dst = vbuf + (size_t)n * CC + blk * 64 + seg * 8;
        asm volatile("global_store_dwordx4 %0, %1, off sc0 sc1" :: "v"(dst), "v"(val) : "memory");
    }

    float logaccq[4] = {0.f, 0.f, 0.f, 0.f};
    char* vl = (char*)vlds;
    const int rkey = (llo & 7) << 4;
    const int rbase = llo * 2048 + lhi * 16;

    for (int t = 1; t < TT; t++) {
        // emission gather for this step (cached, read-only)
        float epf[4];
        #pragma unroll
        for (int q = 0; q < 4; q++)
            epf[q] = bf2f(eprob[(size_t)toks[(lhi * 4 + q) * TT + t] * CC + jglob]);

        // coherent load + sentinel retry + LDS stage of full v[t-1]
        load_stage(vbuf + (size_t)(t - 1) * (NN * CC), th, vl);
        __syncthreads();

        // MFMA: main chain (4-deep) + ones-chain (2-deep) for row sums S_n
        f32x4 ac0 = {0,0,0,0}, ac1 = {0,0,0,0}, ac2 = {0,0,0,0}, ac3 = {0,0,0,0};
        f32x4 ao0 = {0,0,0,0}, ao1 = {0,0,0,0};
        #pragma unroll
        for (int kt = 0; kt < 32; kt += 4) {
            s8b a0 = *(const s8b*)(vl + ((rbase + (kt + 0) * 64) ^ rkey));
            s8b a1 = *(const s8b*)(vl + ((rbase + (kt + 1) * 64) ^ rkey));
            s8b a2 = *(const s8b*)(vl + ((rbase + (kt + 2) * 64) ^ rkey));
            s8b a3 = *(const s8b*)(vl + ((rbase + (kt + 3) * 64) ^ rkey));
            ac0 = __builtin_amdgcn_mfma_f32_16x16x32_bf16(a0, bfr[kt + 0], ac0, 0, 0, 0);
            ao0 = __builtin_amdgcn_mfma_f32_16x16x32_bf16(a0, ones,        ao0, 0, 0, 0);
            ac1 = __builtin_amdgcn_mfma_f32_16x16x32_bf16(a1, bfr[kt + 1], ac1, 0, 0, 0);
            ao1 = __builtin_amdgcn_mfma_f32_16x16x32_bf16(a1, ones,        ao1, 0, 0, 0);
            ac2 = __builtin_amdgcn_mfma_f32_16x16x32_bf16(a2, bfr[kt + 2], ac2, 0, 0, 0);
            ao0 = __builtin_amdgcn_mfma_f32_16x16x32_bf16(a2, ones,        ao0, 0, 0, 0);
            ac3 = __builtin_amdgcn_mfma_f32_16x16x32_bf16(a3, bfr[kt + 3], ac3, 0, 0, 0);
            ao1 = __builtin_amdgcn_mfma_f32_16x16x32_bf16(a3, ones,        ao1, 0, 0, 0);
        }
        f32x4 acc = (ac0 + ac1) + (ac2 + ac3);
        f32x4 aco = ao0 + ao1;   // aco[q] = S_{n=lhi*4+q} (all columns identical)

        // epilogue: scale by 1/S, emission multiply, stage for publish
        #pragma unroll
        for (int q = 0; q < 4; q++) {
            float S = aco[q];
            logaccq[q] += __logf(S);
            float vq = acc[q] * (1.0f / S) * epf[q];
            vtile[lhi * 4 + q][w * 16 + llo] = f2bf(vq);
        }
        __syncthreads();

        // publish: 128 lanes store 16B canonical chunks
        if (th < 128) {
            int n = th >> 3, seg = th & 7;
            s8b val = *(const s8b*)&vtile[n][seg * 8];
            unsigned short* dst = vbuf + (size_t)t * (NN * CC) + (size_t)n * CC + blk * 64 + seg * 8;
            asm volatile("global_store_dwordx4 %0, %1, off sc0 sc1" :: "v"(dst), "v"(val) : "memory");
        }
    }

    // ---- final: block 0 loads v[255], computes S_255 via ones-MFMA, writes output ----
    if (blk == 0) {
        load_stage(vbuf + (size_t)255 * (NN * CC), th, vl);
        __syncthreads();
        f32x4 ao0 = {0,0,0,0}, ao1 = {0,0,0,0};
        #pragma unroll
        for (int kt = 0; kt < 32; kt += 2) {
            s8b a0 = *(const s8b*)(vl + ((rbase + (kt + 0) * 64) ^ rkey));
            s8b a1 = *(const s8b*)(vl + ((rbase + (kt + 1) * 64) ^ rkey));
            ao0 = __builtin_amdgcn_mfma_f32_16x16x32_bf16(a0, ones, ao0, 0, 0, 0);
            ao1 = __builtin_amdgcn_mfma_f32_16x16x32_bf16(a1, ones, ao1, 0, 0, 0);
        }
        f32x4 acoF = ao0 + ao1;
        if (w == 0 && llo == 0) {
            #pragma unroll
            for (int q = 0; q < 4; q++)
                fin[lhi * 4 + q] = logaccq[q] + __logf(acoF[q]);
        }
        __syncthreads();
        if (th == 0) {
            float tot = 0.f;
            for (int n = 0; n < 16; n++) tot += fin[n];
            outp[0] = tot;
        }
    }
}

extern "C" void kernel_launch(void* const* d_in, const int* in_sizes, int n_in,
                              void* d_out, int out_size, void* d_ws, size_t ws_size,
                              hipStream_t stream) {
    const int*   text      = (const int*)  d_in[0];
    const float* start_emb = (const float*)d_in[1];
    const float* sw1 = (const float*)d_in[2];
    const float* sb1 = (const float*)d_in[3];
    const float* sw2 = (const float*)d_in[4];
    const float* sb2 = (const float*)d_in[5];
    const float* sw3 = (const float*)d_in[6];
    const float* sb3 = (const float*)d_in[7];
    const float* state_emb = (const float*)d_in[8];
    const float* tw1 = (const float*)d_in[9];
    const float* tb1 = (const float*)d_in[10];
    const float* tw2 = (const float*)d_in[11];
    const float* tb2 = (const float*)d_in[12];
    const float* tw3 = (const float*)d_in[13];
    const float* tb3 = (const float*)d_in[14];
    const float* pre_emb = (const float*)d_in[15];
    const float* ew1 = (const float*)d_in[16];
    const float* eb1 = (const float*)d_in[17];
    const float* ew2 = (const float*)d_in[18];
    const float* eb2 = (const float*)d_in[19];
    const float* ew3 = (const float*)d_in[20];
    const float* eb3 = (const float*)d_in[21];

    char* wsp = (char*)d_ws;
    // layout (bytes):
    //   PB     [0, 2 MiB)
    //   emitT  [2 MiB, 22,577,152)            (VV*CC*2 = 20,480,000)
    //   res_s  [2 MiB, 3 MiB)    \ overlay emitT head: dead before k_emitg writes
    //   res_t  [3 MiB, 4 MiB)    /
    //   res_e  [22,577,152, 23,625,728)       (read by k_emitg, outside emitT)
    //   slog   [23,625,728, +4 KiB)
    //   lse    [23,629,824, +4 KiB)
    //   epart2 [23,633,920, +320 KiB)         (40 x 1024 x 2 f32)
    //   vbuf   [23 MiB = 24,117,248, 31 MiB)  sentinel-armed (8 MiB)
    unsigned short* PB    = (unsigned short*)(wsp);
    unsigned short* emitT = (unsigned short*)(wsp + ((size_t)2 << 20));
    float* res_s = (float*)(wsp + ((size_t)2 << 20));
    float* res_t = (float*)(wsp + ((size_t)3 << 20));
    float* res_e = (float*)(wsp + 22577152u);
    float* slog  = (float*)(wsp + 23625728u);
    float* lse   = (float*)(wsp + 23629824u);
    float* epart2= (float*)(wsp + 23633920u);
    unsigned short* vbuf = (unsigned short*)(wsp + ((size_t)23 << 20));
    float* outp  = (float*)d_out;

    if (ws_size < ((size_t)31 << 20)) return;  // leaves poison -> visible failure

    // arm sentinels (nothing else lives in this region)
    hipMemsetAsync(vbuf, 0xFF, (size_t)TT * NN * CC * sizeof(unsigned short), stream);

    ResArgs3 ra;
    ra.a[0] = { start_emb, sw1, sb1, sw2, sb2, res_s };
    ra.a[1] = { state_emb, tw1, tb1, tw2, tb2, res_t };
    ra.a[2] = { pre_emb,   ew1, eb1, ew2, eb2, res_e };

    hipLaunchKernelGGL(k_res,   dim3(64, 3),   dim3(256), 0, stream, ra);
    hipLaunchKernelGGL(k_slog,  dim3(4),       dim3(256), 0, stream, res_s, sw3, sb3, slog);
    hipLaunchKernelGGL(k_pt,    dim3(256),     dim3(256), 0, stream, res_t, tw3, tb3, PB);
    hipLaunchKernelGGL(k_emitg, dim3(NVB, 16), dim3(256), 0, stream, res_e, ew3, eb3, emitT, epart2);
    hipLaunchKernelGGL(k_lse,   dim3(4),       dim3(256), 0, stream, epart2, lse);
    hipLaunchKernelGGL(k_eprob, dim3(5000),    dim3(256), 0, stream, emitT, lse);
    hipLaunchKernelGGL(k_fwd,   dim3(NB),      dim3(256), 0, stream,
                       PB, emitT, slog, text, vbuf, outp);
}